// Round 2
// baseline (429.230 us; speedup 1.0000x reference)
//
#include <hip/hip_runtime.h>

// NLWT fused: 2x2 im2col -> M1 -> circular roll of subbands -> M2 -> subband-
// major concat. Each thread owns one column-pair (2 output cols, 6 input cols
// incl. halo) and a vertical strip of RS=16 output rows. Input rows 2i,2i+1
// are carried in registers from the previous iteration, so only 2 fresh rows
// are loaded per output row: HBM read amplification (2*RS+2)/(2*RS) = 1.06x
// (vs 2.0x for the row-independent version, whose row halo missed L2 because
// adjacent row-blocks land on different XCDs). Column halo (float2 loads) hits
// the same cache lines as the neighboring lane's float4 -> absorbed by L1.

#define H  512
#define W  512
#define H1 256
#define W1 256
#define RS 16   // output rows per thread strip

#define DOT(m0, m1, m2, m3, q, r, s, t) \
    fmaf((m0), (q), fmaf((m1), (r), fmaf((m2), (s), (m3) * (t))))

__global__ __launch_bounds__(256) void nlwt_kernel(const float* __restrict__ x,
                                                   float* __restrict__ out) {
    const int bc    = blockIdx.y;                              // image: b*32+c
    const int strip = (blockIdx.x << 1) + (threadIdx.x >> 7);  // 0..15
    const int jp    = threadIdx.x & 127;                       // col pair
    const int c0    = jp << 2;                                 // input col base
    const int c4    = (c0 + 4) & (W - 1);                      // halo col (wrap)
    const int j     = jp << 1;                                 // output col
    const int i0    = strip * RS;                              // first out row

    const float* img = x + (size_t)bc * (H * W);
    const int b = bc >> 5, ch = bc & 31;
    float* obase = out + ((size_t)(b * 128 + ch) * (H1 * W1)) + (size_t)i0 * W1 + j;
    const size_t sstride = (size_t)32 * H1 * W1;  // subband stride (channels)

    // Prologue: carried rows 2*i0, 2*i0+1
    const float* p = img + (i0 << 1) * W;
    float4 A  = *(const float4*)(p + c0);
    float2 Ae = *(const float2*)(p + c4);
    float4 B  = *(const float4*)(p + W + c0);
    float2 Be = *(const float2*)(p + W + c4);

#pragma unroll
    for (int k = 0; k < RS; ++k) {
        const int i  = i0 + k;
        const int r2 = ((i << 1) + 2) & (H - 1);  // wrapped next block row
        const float* q = img + r2 * W;
        float4 C  = *(const float4*)(q + c0);
        float2 Ce = *(const float2*)(q + c4);
        float4 D  = *(const float4*)(q + W + c0);
        float2 De = *(const float2*)(q + W + c4);

        // After-roll x1r at pixel (i,j):  t0=M1r0.blk(i,j)  t1=M1r1.blk(i+1,j)
        //                                 t2=M1r2.blk(i,j+1) t3=M1r3.blk(i+1,j+1)
        const float t0 = DOT( 0.8664f,  0.1026f,  0.4852f, -0.0574f, A.x, A.y, B.x, B.y);
        const float t2 = DOT( 0.4852f,  0.0574f, -0.8664f,  0.1026f, A.z, A.w, B.z, B.w);
        const float u0 = DOT( 0.8664f,  0.1026f,  0.4852f, -0.0574f, A.z, A.w, B.z, B.w);
        const float u2 = DOT( 0.4852f,  0.0574f, -0.8664f,  0.1026f, Ae.x, Ae.y, Be.x, Be.y);
        const float t1 = DOT(-0.1026f,  0.8664f, -0.0574f, -0.4852f, C.x, C.y, D.x, D.y);
        const float t3 = DOT( 0.0574f, -0.4852f, -0.1026f, -0.8664f, C.z, C.w, D.z, D.w);
        const float u1 = DOT(-0.1026f,  0.8664f, -0.0574f, -0.4852f, C.z, C.w, D.z, D.w);
        const float u3 = DOT( 0.0574f, -0.4852f, -0.1026f, -0.8664f, Ce.x, Ce.y, De.x, De.y);

        float* ob = obase + (size_t)k * W1;
        float2 o;
        o.x = DOT( 1.3968f,  0.2212f, -0.2212f, -1.3968f, t0, t1, t2, t3);
        o.y = DOT( 1.3968f,  0.2212f, -0.2212f, -1.3968f, u0, u1, u2, u3);
        *(float2*)(ob) = o;
        o.x = DOT(-0.2212f,  1.3968f, -1.3968f,  0.2212f, t0, t1, t2, t3);
        o.y = DOT(-0.2212f,  1.3968f, -1.3968f,  0.2212f, u0, u1, u2, u3);
        *(float2*)(ob + sstride) = o;
        o.x = DOT(-0.5412f, -1.3066f, -1.3066f, -0.5412f, t0, t1, t2, t3);
        o.y = DOT(-0.5412f, -1.3066f, -1.3066f, -0.5412f, u0, u1, u2, u3);
        *(float2*)(ob + 2 * sstride) = o;
        o.x = DOT( 1.3066f, -0.5412f, -0.5412f,  1.3066f, t0, t1, t2, t3);
        o.y = DOT( 1.3066f, -0.5412f, -0.5412f,  1.3066f, u0, u1, u2, u3);
        *(float2*)(ob + 3 * sstride) = o;

        // shift: fresh rows become carried rows
        A = C; Ae = Ce; B = D; Be = De;
    }
}

extern "C" void kernel_launch(void* const* d_in, const int* in_sizes, int n_in,
                              void* d_out, int out_size, void* d_ws, size_t ws_size,
                              hipStream_t stream) {
    const float* x = (const float*)d_in[0];
    float* out = (float*)d_out;
    // 256 images; 16 row-strips/image; 2 strips per 256-thread block -> 8 x-blocks
    dim3 grid(8, 256);
    nlwt_kernel<<<grid, 256, 0, stream>>>(x, out);
}